// Round 3
// baseline (147.663 us; speedup 1.0000x reference)
//
#include <hip/hip_runtime.h>

typedef __attribute__((ext_vector_type(8))) __bf16 bf16x8;
typedef __attribute__((ext_vector_type(2))) __bf16 bf16x2;
typedef __attribute__((ext_vector_type(4))) float f32x4;
typedef __attribute__((ext_vector_type(4))) unsigned int u32x4;

#define AS1 __attribute__((address_space(1)))
#define AS3 __attribute__((address_space(3)))

__device__ __forceinline__ unsigned short f2b(float f) {
    union { float f; unsigned int u; } c; c.f = f;
    unsigned int r = c.u + 0x7fffu + ((c.u >> 16) & 1u);
    return (unsigned short)(r >> 16);
}

__device__ __forceinline__ unsigned int pack2(float a, float b) {
    bf16x2 t;
    t[0] = (__bf16)a;
    t[1] = (__bf16)b;
    return __builtin_bit_cast(unsigned int, t);
}

__device__ __forceinline__ void gload_lds16(const void* g, void* l) {
    __builtin_amdgcn_global_load_lds((const AS1 unsigned int*)g,
                                     (AS3 unsigned int*)l, 16, 0, 0);
}

// ------------- fp32 -> bf16 convert (both inputs, one launch) -------------
// hs -> linear bf16. Wqkv -> MFMA-FRAGMENT layout:
//   addr(row,col) = (kt*192 + n16)*512 + lane*8 + e
//   kt=col>>5, kg=(col>>3)&3, e=col&7, n16=row>>4, fr=row&15, lane=kg*16+fr
// so a wave's B-frag load in the GEMM is 64 lanes x 16B CONTIGUOUS (1KB).
__global__ void cvt2_kernel(const float* __restrict__ in0,
                            unsigned short* __restrict__ out0, int n0,
                            const float* __restrict__ in1,
                            unsigned short* __restrict__ out1, int n1) {
    int i = blockIdx.x * blockDim.x + threadIdx.x;
    int stride = gridDim.x * blockDim.x;
    const int nt = n0 + n1;
    for (; i < nt; i += stride) {
        if (i < n0) {
            float4 v = reinterpret_cast<const float4*>(in0)[i];
            ushort4 o;
            o.x = f2b(v.x); o.y = f2b(v.y); o.z = f2b(v.z); o.w = f2b(v.w);
            reinterpret_cast<ushort4*>(out0)[i] = o;
        } else {
            const int j = i - n0;
            const int E = j * 4;
            const int row = E >> 10;
            const int col = E & 1023;
            float4 v = reinterpret_cast<const float4*>(in1)[j];
            ushort4 o;
            o.x = f2b(v.x); o.y = f2b(v.y); o.z = f2b(v.z); o.w = f2b(v.w);
            const int kt = col >> 5, kg = (col >> 3) & 3, e = col & 7;
            const int n16 = row >> 4, fr = row & 15;
            const size_t oaddr = ((size_t)(kt * 192 + n16) << 9)
                               + ((kg * 16 + fr) << 3) + e;
            *reinterpret_cast<ushort4*>(out1 + oaddr) = o;
        }
    }
}

// ---------------- QKV GEMM: C[8192][3072] = hs @ W^T + bias ----------------
// r3: B removed from LDS. B-frags load straight from global (frag-order
// layout written by cvt2; 4 wm-waves hit the same 8KB panel in L1).
// r1/r2 were LDS-traffic-bound: 176KB/CU-step (reads 128KB + stage 48KB)
// = 1400-2000cy vs MFMA 1240cy. Now LDS = A only: 96KB/CU-step < MFMA.
// LDS 3 x 16KB = 48KB (2 blocks/CU), ONE barrier per K-step.
// Staging protocol: vmcnt(6) before bar(t) guarantees stage(t-2) done
// (in-order vmem retirement: >=6 younger ops - 2 stage(t-1) + 4 bf(t) -
// in any intra-region schedule); tail uses 6 then 4.
__global__ __launch_bounds__(512, 4) void qkv_gemm(
    const unsigned short* __restrict__ A,
    const unsigned short* __restrict__ Bw,
    const float* __restrict__ bias,
    unsigned short* __restrict__ qb,
    unsigned short* __restrict__ kb,
    unsigned short* __restrict__ vb)
{
    __shared__ __align__(16) char smem[49152];  // 3 x A 16K
    const int tid = threadIdx.x;
    const int lane = tid & 63, w = tid >> 6;     // 8 waves
    const int wm = w >> 1, wn = w & 1;
    const int wg = (blockIdx.x & 7) * 96 + (blockIdx.x >> 3);
    const int mt = wg / 24;
    const int nt = wg % 24;
    const int fr = lane & 15, kg = lane >> 4;

    // A staging: 16 rows x 64B per gload; lane l -> row (l>>2), slot (l&3)
    const int sr = lane >> 2;
    const int g  = (lane & 3) ^ ((sr >> 1) & 3);   // pre-swizzled src granule
    const unsigned short* a_srcg = A + (size_t)(mt * 256 + w * 16 + sr) * 1024 + g * 8;
    // B frag base: frag-order layout, wave reads contiguous 1KB per frag
    const unsigned short* bfp = Bw + (((size_t)(nt * 8 + wn * 4)) << 9) + lane * 8;

    f32x4 acc[4][4] = {};
    const int pg = (kg ^ ((fr >> 1) & 3)) * 16;    // A read-side slot swizzle
    const int aoffA = (wm * 64 + fr) * 64;

#define STAGE_FULL(buf, kt) do {                                    \
    char* Sb_ = smem + (buf) * 16384 + w * 1024;                    \
    const size_t ko_ = (size_t)(kt) * 32;                           \
    gload_lds16(a_srcg + ko_,          Sb_);                        \
    gload_lds16(a_srcg + 131072 + ko_, Sb_ + 8192);                 \
} while (0)

#define MM(m_, n_) do {                                                        \
    acc[m_][n_] = __builtin_amdgcn_mfma_f32_16x16x32_bf16(                     \
        af[m_], bf[n_], acc[m_][n_], 0, 0, 0);                                 \
} while (0)

// per K-32 step: bf global loads -> vmcnt -> bar -> af ds_reads + stage
// -> 16 MFMA (compiler inserts fine-grained lgkm/vm waits for frags).
#define GT(CUR, PRE, kt, DOSTAGE, WNSTR) do {                                  \
    const char* Ab_ = smem + (CUR) * 16384;                                    \
    char* Sb_ = smem + (PRE) * 16384 + w * 1024;                               \
    const size_t ko_ = (size_t)((kt) + 2) * 32;                                \
    const unsigned short* bq_ = bfp + (size_t)(kt) * 98304;                    \
    bf16x8 af[4], bf[4];                                                       \
    _Pragma("unroll")                                                          \
    for (int n = 0; n < 4; ++n)                                                \
        bf[n] = *reinterpret_cast<const bf16x8*>(bq_ + (n << 9));              \
    asm volatile("s_waitcnt vmcnt(" WNSTR ")" ::: "memory");                   \
    __builtin_amdgcn_s_barrier();                                              \
    _Pragma("unroll")                                                          \
    for (int m = 0; m < 4; ++m)                                                \
        af[m] = *reinterpret_cast<const bf16x8*>(Ab_ + aoffA + m * 1024 + pg); \
    if (DOSTAGE) {                                                             \
        gload_lds16(a_srcg + ko_,          Sb_);                               \
        gload_lds16(a_srcg + 131072 + ko_, Sb_ + 8192);                        \
    }                                                                          \
    __builtin_amdgcn_s_setprio(1);                                             \
    MM(0, 0); MM(1, 0); MM(2, 0); MM(3, 0);                                    \
    MM(0, 1); MM(1, 1); MM(2, 1); MM(3, 1);                                    \
    MM(0, 2); MM(1, 2); MM(2, 2); MM(3, 2);                                    \
    MM(0, 3); MM(1, 3); MM(2, 3); MM(3, 3);                                    \
    __builtin_amdgcn_s_setprio(0);                                             \
} while (0)

    STAGE_FULL(0, 0);
    STAGE_FULL(1, 1);
#pragma unroll 1
    for (int it = 0; it < 10; ++it) {
        const int t0 = it * 3;
        GT(0, 2, t0 + 0, 1, "6");
        GT(1, 0, t0 + 1, 1, "6");
        GT(2, 1, t0 + 2, 1, "6");
    }
    GT(0, 2, 30, 0, "6");
    GT(1, 0, 31, 0, "4");
    __syncthreads();

    const int sidx = nt >> 3;
    float bv[4];
#pragma unroll
    for (int n = 0; n < 4; ++n) bv[n] = bias[nt * 128 + wn * 64 + n * 16 + fr];

    unsigned short* Cs = (unsigned short*)smem;

    if (sidx < 2) {
        unsigned short* dstb = (sidx == 0) ? qb : kb;
        const float sc = (sidx == 0) ? 0.1803368801111f : 1.0f;
#pragma unroll
        for (int p = 0; p < 2; ++p) {
            if ((wm >> 1) == p) {
                const int r0 = (wm & 1) * 64;
#pragma unroll
                for (int m = 0; m < 4; ++m)
#pragma unroll
                    for (int n = 0; n < 4; ++n)
#pragma unroll
                        for (int r = 0; r < 4; ++r)
                            Cs[(r0 + m * 16 + kg * 4 + r) * 136 + wn * 64 + n * 16 + fr] =
                                f2b((acc[m][n][r] + bv[n]) * sc);
            }
            __syncthreads();
#pragma unroll
            for (int itc = 0; itc < 4; ++itc) {
                const int task = itc * 512 + tid;
                const int rl = task >> 4;
                const int i16 = task & 15;
                const int t = mt * 256 + p * 128 + rl;
                const int b_ = t >> 10, s = t & 1023;
                const int head = ((nt * 128 + i16 * 8) >> 6) & 15;
                u32x4 v = *reinterpret_cast<const u32x4*>(Cs + rl * 136 + i16 * 8);
                *reinterpret_cast<u32x4*>(
                    dstb + ((size_t)(b_ * 16 + head) * 1024 + s) * 64 + (i16 & 7) * 8) = v;
            }
            __syncthreads();
        }
    } else {
#pragma unroll
        for (int p = 0; p < 2; ++p) {
            if ((wm >> 1) == p) {
                const int r0 = (wm & 1) * 64;
#pragma unroll
                for (int m = 0; m < 4; ++m)
#pragma unroll
                    for (int n = 0; n < 4; ++n)
#pragma unroll
                        for (int j = 0; j < 2; ++j) {
                            unsigned int pk = pack2(acc[m][n][2 * j] + bv[n],
                                                    acc[m][n][2 * j + 1] + bv[n]);
                            *reinterpret_cast<unsigned int*>(
                                Cs + (wn * 64 + n * 16 + fr) * 136
                                   + r0 + m * 16 + kg * 4 + 2 * j) = pk;
                        }
            }
            __syncthreads();
#pragma unroll
            for (int itc = 0; itc < 4; ++itc) {
                const int task = itc * 512 + tid;
                const int c = task >> 4;
                const int i16 = task & 15;
                const int col = nt * 128 + c;
                const int head = (col >> 6) & 15;
                const int d = col & 63;
                const int b_ = (mt * 256) >> 10;
                const int s0 = (mt * 256 & 1023) + p * 128 + i16 * 8;
                u32x4 v = *reinterpret_cast<const u32x4*>(Cs + c * 136 + i16 * 8);
                *reinterpret_cast<u32x4*>(
                    vb + (size_t)((b_ * 16 + head) * 64 + d) * 1024 + s0) = v;
            }
            __syncthreads();
        }
    }
#undef STAGE_FULL
#undef GT
#undef MM
}

// ---------------- flash attention (swapped QK^T, permuted-K LDS) ----------
// grid: 128 bh * 8 qtiles of 128 rows; block 256 (4 waves x 32 q). KVB=64,
// qf=2 -> ~120 live VGPR; __launch_bounds__(256,4) targets 4 waves/SIMD
// (4 blocks/CU, grid 1024 = exactly 4/CU) to hide barrier/exp latency
// (r13 showed LDS-traffic halving = null -> latency-bound).
#define KVB 64
__global__ __launch_bounds__(256, 4) void attn_kernel(
    const unsigned short* __restrict__ qb,
    const unsigned short* __restrict__ kb,
    const unsigned short* __restrict__ vb,
    float* __restrict__ out)
{
    __shared__ __align__(16) char asmem[32768];  // 2 bufs x (K 8K + V 8K)
    const int tid = threadIdx.x;
    const int lane = tid & 63, w = tid >> 6;
    // XCD-chunked swizzle: 1024 = 8 * 128 (bijective)
    const int wg = (blockIdx.x & 7) * 128 + (blockIdx.x >> 3);
    const int bh = wg >> 3;
    const int qt = wg & 7;
    const int b_ = bh >> 4, h_ = bh & 15;
    const int fr = lane & 15, kg = lane >> 4;

    const unsigned short* qp = qb + ((size_t)bh * 1024 + qt * 128) * 64;
    const unsigned short* kp = kb + (size_t)bh * 1024 * 64;
    const unsigned short* vp = vb + (size_t)bh * 64 * 1024;

    bf16x8 qfr[2][2];
#pragma unroll
    for (int qf = 0; qf < 2; ++qf) {
        const unsigned short* qr = qp + (w * 32 + qf * 16 + fr) * 64 + kg * 8;
        qfr[qf][0] = *reinterpret_cast<const bf16x8*>(qr);
        qfr[qf][1] = *reinterpret_cast<const bf16x8*>(qr + 32);
    }

    float m_q[2] = {-1e30f, -1e30f}, l_q[2] = {0.f, 0.f};
    f32x4 o_acc[2][4] = {};

    const int ksr = w * 8 + (lane >> 3);   // staging row within 32-row group
    const int kcb = (lane & 7) * 16;       // granule byte within 128B row

#define ASTAGE(buf, kvt) do {                                                  \
    const int kv0_ = (kvt) * KVB;                                              \
    char* Kb_ = asmem + (buf) * 16384 + w * 1024;                              \
    char* Vb_ = Kb_ + 8192;                                                    \
    _Pragma("unroll")                                                          \
    for (int i = 0; i < 2; ++i) {                                              \
        const int st = i * 32 + ksr;                                           \
        const int key = ((st >> 5) << 5) | (((st & 15) >> 2) << 3)             \
                      | (((st >> 4) & 1) << 2) | (st & 3);                     \
        const int scb = kcb ^ ((st & 7) << 4);                                 \
        gload_lds16(kp + (size_t)(kv0_ + key) * 64 + (scb >> 1),               \
                    Kb_ + i * 4096);                                           \
        const int d_ = i * 32 + ksr;                                           \
        const int svb = kcb ^ ((d_ & 7) << 4);                                 \
        gload_lds16(vp + (size_t)d_ * 1024 + kv0_ + (svb >> 1),                \
                    Vb_ + i * 4096);                                           \
    }                                                                          \
} while (0)

#define ACOMP(buf) do {                                                        \
    const char* Kb = asmem + (buf) * 16384;                                    \
    const char* Vb = Kb + 8192;                                                \
    f32x4 sacc[2][4] = {};                                                     \
    __builtin_amdgcn_s_setprio(1);                                             \
    _Pragma("unroll")                                                          \
    for (int jt = 0; jt < 4; ++jt) {                                           \
        _Pragma("unroll")                                                      \
        for (int ks = 0; ks < 2; ++ks) {                                       \
            const int cb = (ks * 64 + kg * 16) ^ ((fr & 7) << 4);              \
            bf16x8 kf = *reinterpret_cast<const bf16x8*>(                      \
                Kb + (jt * 16 + fr) * 128 + cb);                               \
            _Pragma("unroll")                                                  \
            for (int qf = 0; qf < 2; ++qf)                                     \
                sacc[qf][jt] = __builtin_amdgcn_mfma_f32_16x16x32_bf16(        \
                    kf, qfr[qf][ks], sacc[qf][jt], 0, 0, 0);                   \
        }                                                                      \
    }                                                                          \
    __builtin_amdgcn_s_setprio(0);                                             \
    unsigned int P2[2][4][2];                                                  \
    _Pragma("unroll")                                                          \
    for (int qf = 0; qf < 2; ++qf) {                                           \
        float mx = -1e30f;                                                     \
        _Pragma("unroll")                                                      \
        for (int jt = 0; jt < 4; ++jt) {                                       \
            float a = fmaxf(fmaxf(sacc[qf][jt][0], sacc[qf][jt][1]),           \
                            fmaxf(sacc[qf][jt][2], sacc[qf][jt][3]));          \
            mx = fmaxf(mx, a);                                                 \
        }                                                                      \
        mx = fmaxf(mx, __shfl_xor(mx, 16, 64));                                \
        mx = fmaxf(mx, __shfl_xor(mx, 32, 64));                                \
        if (__any(mx > m_q[qf] + 8.0f)) {                                      \
            const float mn = fmaxf(m_q[qf], mx);                               \
            const float corr = __builtin_amdgcn_exp2f(m_q[qf] - mn);           \
            m_q[qf] = mn;                                                      \
            l_q[qf] *= corr;                                                   \
            float cr[4];                                                       \
            _Pragma("unroll")                                                  \
            for (int r = 0; r < 4; ++r)                                        \
                cr[r] = __shfl(corr, kg * 4 + r, 64);                          \
            _Pragma("unroll")                                                  \
            for (int d0 = 0; d0 < 4; ++d0)                                     \
                _Pragma("unroll")                                              \
                for (int r = 0; r < 4; ++r) o_acc[qf][d0][r] *= cr[r];         \
        }                                                                      \
        const float mn_ = m_q[qf];                                             \
        float rs = 0.f;                                                        \
        _Pragma("unroll")                                                      \
        for (int jt = 0; jt < 4; ++jt) {                                       \
            float p0 = __builtin_amdgcn_exp2f(sacc[qf][jt][0] - mn_);          \
            float p1 = __builtin_amdgcn_exp2f(sacc[qf][jt][1] - mn_);          \
            float p2 = __builtin_amdgcn_exp2f(sacc[qf][jt][2] - mn_);          \
            float p3 = __builtin_amdgcn_exp2f(sacc[qf][jt][3] - mn_);          \
            rs += (p0 + p1) + (p2 + p3);                                       \
            P2[qf][jt][0] = pack2(p0, p1);                                     \
            P2[qf][jt][1] = pack2(p2, p3);                                     \
        }                                                                      \
        rs += __shfl_xor(rs, 16, 64);                                          \
        rs += __shfl_xor(rs, 32, 64);                                          \
        l_q[qf] += rs;                                                         \
    }                                                                          \
    __builtin_amdgcn_s_setprio(1);                                             \
    _Pragma("unroll")                                                          \
    for (int c = 0; c < 2; ++c) {                                              \
        bf16x8 pa[2];                                                          \
        _Pragma("unroll")                                                      \
        for (int qf = 0; qf < 2; ++qf) {                                       \
            u32x4 pw = { P2[qf][2 * c][0], P2[qf][2 * c][1],                   \
                         P2[qf][2 * c + 1][0], P2[qf][2 * c + 1][1] };         \
            pa[qf] = __builtin_bit_cast(bf16x8, pw);                           \
        }                                                                      \
        _Pragma("unroll")                                                      \
        for (int d0 = 0; d0 < 4; ++d0) {                                       \
            const int dd = d0 * 16 + fr;                                       \
            const int cbv = (c * 64 + kg * 16) ^ ((dd & 7) << 4);              \
            bf16x8 vf = *reinterpret_cast<const bf16x8*>(Vb + dd * 128 + cbv); \
            _Pragma("unroll")                                                  \
            for (int qf = 0; qf < 2; ++qf)                                     \
                o_acc[qf][d0] = __builtin_amdgcn_mfma_f32_16x16x32_bf16(       \
                    pa[qf], vf, o_acc[qf][d0], 0, 0, 0);                       \
        }                                                                      \
    }                                                                          \
    __builtin_amdgcn_s_setprio(0);                                             \
} while (0)

    ASTAGE(0, 0);
#pragma unroll 1
    for (int t = 0; t < 15; ++t) {
        ASTAGE((t + 1) & 1, t + 1);
        asm volatile("s_waitcnt vmcnt(4) lgkmcnt(0)" ::: "memory");
        __builtin_amdgcn_s_barrier();
        ACOMP(t & 1);
        asm volatile("s_waitcnt lgkmcnt(0)" ::: "memory");
        __builtin_amdgcn_s_barrier();
    }
    asm volatile("s_waitcnt vmcnt(0) lgkmcnt(0)" ::: "memory");
    __builtin_amdgcn_s_barrier();
    ACOMP(1);

    // epilogue: normalize and write fp32 out[t][h*64+d]
#pragma unroll
    for (int qf = 0; qf < 2; ++qf) {
        float linv[4];
#pragma unroll
        for (int r = 0; r < 4; ++r)
            linv[r] = 1.0f / __shfl(l_q[qf], kg * 4 + r, 64);
        const int trow = b_ * 1024 + qt * 128 + w * 32 + qf * 16;
#pragma unroll
        for (int d0 = 0; d0 < 4; ++d0) {
            const int c = h_ * 64 + d0 * 16 + fr;
#pragma unroll
            for (int r = 0; r < 4; ++r)
                out[(size_t)(trow + kg * 4 + r) * 1024 + c] = o_acc[qf][d0][r] * linv[r];
        }
    }
#undef ASTAGE
#undef ACOMP
}

extern "C" void kernel_launch(void* const* d_in, const int* in_sizes, int n_in,
                              void* d_out, int out_size, void* d_ws, size_t ws_size,
                              hipStream_t stream)
{
    const float* hs   = (const float*)d_in[0];
    const float* Wqkv = (const float*)d_in[1];
    const float* Bqkv = (const float*)d_in[2];
    float* out = (float*)d_out;

    char* ws = (char*)d_ws;
    unsigned short* hsb = (unsigned short*)(ws);                        // 16 MB
    unsigned short* wb  = (unsigned short*)(ws + (size_t)16 * 1048576); //  6 MB
    unsigned short* qb  = (unsigned short*)(ws + (size_t)22 * 1048576); // 16 MB
    unsigned short* kb  = (unsigned short*)(ws + (size_t)38 * 1048576); // 16 MB
    unsigned short* vb  = (unsigned short*)(ws + (size_t)54 * 1048576); // 16 MB

    cvt2_kernel<<<2048, 256, 0, stream>>>(hs, hsb, 8192 * 1024 / 4,
                                          Wqkv, wb, 3072 * 1024 / 4);
    qkv_gemm<<<768, 512, 0, stream>>>(hsb, wb, Bqkv, qb, kb, vb);
    attn_kernel<<<1024, 256, 0, stream>>>(qb, kb, vb, out);
}

// Round 4
// 126.976 us; speedup vs baseline: 1.1629x; 1.1629x over previous
//
#include <hip/hip_runtime.h>

typedef __attribute__((ext_vector_type(8))) __bf16 bf16x8;
typedef __attribute__((ext_vector_type(2))) __bf16 bf16x2;
typedef __attribute__((ext_vector_type(4))) float f32x4;
typedef __attribute__((ext_vector_type(4))) unsigned int u32x4;

#define AS1 __attribute__((address_space(1)))
#define AS3 __attribute__((address_space(3)))

__device__ __forceinline__ unsigned short f2b(float f) {
    union { float f; unsigned int u; } c; c.f = f;
    unsigned int r = c.u + 0x7fffu + ((c.u >> 16) & 1u);
    return (unsigned short)(r >> 16);
}

__device__ __forceinline__ unsigned int pack2(float a, float b) {
    bf16x2 t;
    t[0] = (__bf16)a;
    t[1] = (__bf16)b;
    return __builtin_bit_cast(unsigned int, t);
}

__device__ __forceinline__ void gload_lds16(const void* g, void* l) {
    __builtin_amdgcn_global_load_lds((const AS1 unsigned int*)g,
                                     (AS3 unsigned int*)l, 16, 0, 0);
}

// ------------- fp32 -> bf16 convert (both inputs, one launch) -------------
// hs -> linear bf16 (float4 path). Wqkv -> MFMA-FRAGMENT layout via GATHER:
// out element addr = (kt*192 + n16)*512 + lane*8 + e, lane = kg*16+fr,
// source (row,col) = (n16*16+fr, kt*32+kg*8+e). Each thread produces 16
// CONTIGUOUS output bytes (fully coalesced writes, no partial-line RMW —
// r3's scatter-writes caused the 92MB WRITE_SIZE bloat); reads are 2x
// float4, and a wave's 8 reads fully consume 16 input 128B lines.
__global__ void cvt2_kernel(const float* __restrict__ in0,
                            unsigned short* __restrict__ out0, int n0,
                            const float* __restrict__ in1,
                            unsigned short* __restrict__ out1, int n1) {
    int i = blockIdx.x * blockDim.x + threadIdx.x;
    int stride = gridDim.x * blockDim.x;
    const int nt = n0 + n1;
    for (; i < nt; i += stride) {
        if (i < n0) {
            float4 v = reinterpret_cast<const float4*>(in0)[i];
            ushort4 o;
            o.x = f2b(v.x); o.y = f2b(v.y); o.z = f2b(v.z); o.w = f2b(v.w);
            reinterpret_cast<ushort4*>(out0)[i] = o;
        } else {
            const int idx = i - n0;            // one 16B output chunk
            const int blk = idx >> 6;          // kt*192 + n16
            const int lane = idx & 63;
            const int kt = blk / 192, n16 = blk % 192;
            const int kg = lane >> 4, fr = lane & 15;
            const size_t src = (size_t)(n16 * 16 + fr) * 1024 + kt * 32 + kg * 8;
            float4 v0 = *reinterpret_cast<const float4*>(in1 + src);
            float4 v1 = *reinterpret_cast<const float4*>(in1 + src + 4);
            ushort4 o0, o1;
            o0.x = f2b(v0.x); o0.y = f2b(v0.y); o0.z = f2b(v0.z); o0.w = f2b(v0.w);
            o1.x = f2b(v1.x); o1.y = f2b(v1.y); o1.z = f2b(v1.z); o1.w = f2b(v1.w);
            reinterpret_cast<ushort4*>(out1)[2 * idx]     = o0;
            reinterpret_cast<ushort4*>(out1)[2 * idx + 1] = o1;
        }
    }
}

// ---------------- QKV GEMM: C[8192][3072] = hs @ W^T + bias ----------------
// r4: B from global, PREFETCHED ONE FULL K-STEP AHEAD into registers
// (r3 loaded B at use-time -> naked L2 latency each step, MfmaUtil 24%).
// Evidence: MfmaUtil*dur ~= 21us across r1/r3 = MFMA-pipe floor; r1's LDS
// pipe was ~73% busy (2.16GB/256CU @85B/cy = 41us of 56.5) -> LDS-bound.
// Now LDS = A only: 96KB/CU-step ~= 1130cy <= MFMA 1240cy -> MFMA-bound.
// LDS 3 x 16KB bufs (48KB, 2 blocks/CU). ONE barrier per step; every
// ds_read is consumed by an MFMA before the barrier (WAR-safe, no lgkm
// drain needed). End-of-step vmcnt(6) retires stage(t+1): younger ops =
// 4 bf-prefetch + 2 stage. B-frag loads: 4 x 1KB coalesced, 8KB/step
// panel shared by 4 wm-waves via L1.
__global__ __launch_bounds__(512, 4) void qkv_gemm(
    const unsigned short* __restrict__ A,
    const unsigned short* __restrict__ Bw,
    const float* __restrict__ bias,
    unsigned short* __restrict__ qb,
    unsigned short* __restrict__ kb,
    unsigned short* __restrict__ vb)
{
    __shared__ __align__(16) char smem[49152];  // 3 x A 16K
    const int tid = threadIdx.x;
    const int lane = tid & 63, w = tid >> 6;     // 8 waves
    const int wm = w >> 1, wn = w & 1;
    const int wg = (blockIdx.x & 7) * 96 + (blockIdx.x >> 3);
    const int mt = wg / 24;
    const int nt = wg % 24;
    const int fr = lane & 15, kg = lane >> 4;

    // A staging: 16 rows x 64B per gload; lane l -> row (l>>2), slot (l&3)
    const int sr = lane >> 2;
    const int g  = (lane & 3) ^ ((sr >> 1) & 3);   // pre-swizzled src granule
    const unsigned short* a_srcg = A + (size_t)(mt * 256 + w * 16 + sr) * 1024 + g * 8;
    // B frag base: frag-order layout, wave reads contiguous 1KB per frag
    const unsigned short* bfp = Bw + (((size_t)(nt * 8 + wn * 4)) << 9) + lane * 8;

    f32x4 acc[4][4] = {};
    const int pg = (kg ^ ((fr >> 1) & 3)) * 16;    // A read-side slot swizzle
    const int aoffA = (wm * 64 + fr) * 64;

    bf16x8 bfA0, bfA1, bfA2, bfA3;   // B frags for even steps
    bf16x8 bfB0, bfB1, bfB2, bfB3;   // B frags for odd steps

#define STAGE_FULL(buf, kt) do {                                    \
    char* Sb_ = smem + (buf) * 16384 + w * 1024;                    \
    const size_t ko_ = (size_t)(kt) * 32;                           \
    gload_lds16(a_srcg + ko_,          Sb_);                        \
    gload_lds16(a_srcg + 131072 + ko_, Sb_ + 8192);                 \
} while (0)

#define BLOAD(B0, B1, B2, B3, kt) do {                                         \
    const unsigned short* bq_ = bfp + (size_t)(kt) * 98304;                    \
    B0 = *reinterpret_cast<const bf16x8*>(bq_);                                \
    B1 = *reinterpret_cast<const bf16x8*>(bq_ + 512);                          \
    B2 = *reinterpret_cast<const bf16x8*>(bq_ + 1024);                         \
    B3 = *reinterpret_cast<const bf16x8*>(bq_ + 1536);                         \
} while (0)

#define MMn(n_, BF_) do {                                                      \
    acc[0][n_] = __builtin_amdgcn_mfma_f32_16x16x32_bf16(                      \
        af[0], BF_, acc[0][n_], 0, 0, 0);                                      \
    acc[1][n_] = __builtin_amdgcn_mfma_f32_16x16x32_bf16(                      \
        af[1], BF_, acc[1][n_], 0, 0, 0);                                      \
    acc[2][n_] = __builtin_amdgcn_mfma_f32_16x16x32_bf16(                      \
        af[2], BF_, acc[2][n_], 0, 0, 0);                                      \
    acc[3][n_] = __builtin_amdgcn_mfma_f32_16x16x32_bf16(                      \
        af[3], BF_, acc[3][n_], 0, 0, 0);                                      \
} while (0)

// per K-32 step. BFC* = current B frags (already resident), BFN* = next
// (prefetch). One barrier/step at the end, preceded by counted vmcnt.
#define GTN(CUR, PRE, kt, C0, C1, C2, C3, N0, N1, N2, N3, DOSTAGE, PF, WNSTR) \
do {                                                                           \
    const char* Ab_ = smem + (CUR) * 16384;                                    \
    char* Sb_ = smem + (PRE) * 16384 + w * 1024;                               \
    const size_t ko_ = (size_t)((kt) + 2) * 32;                                \
    if (PF) BLOAD(N0, N1, N2, N3, (kt) + 1);                                   \
    bf16x8 af[4];                                                              \
    _Pragma("unroll")                                                          \
    for (int m = 0; m < 4; ++m)                                                \
        af[m] = *reinterpret_cast<const bf16x8*>(Ab_ + aoffA + m * 1024 + pg); \
    if (DOSTAGE) {                                                             \
        gload_lds16(a_srcg + ko_,          Sb_);                               \
        gload_lds16(a_srcg + 131072 + ko_, Sb_ + 8192);                        \
    }                                                                          \
    __builtin_amdgcn_s_setprio(1);                                             \
    MMn(0, C0); MMn(1, C1); MMn(2, C2); MMn(3, C3);                            \
    __builtin_amdgcn_s_setprio(0);                                             \
    asm volatile("s_waitcnt vmcnt(" WNSTR ")" ::: "memory");                   \
    __builtin_amdgcn_s_barrier();                                              \
} while (0)

    STAGE_FULL(0, 0);
    STAGE_FULL(1, 1);
    BLOAD(bfA0, bfA1, bfA2, bfA3, 0);
    asm volatile("s_waitcnt vmcnt(6)" ::: "memory");  // stage(0) done
    __builtin_amdgcn_s_barrier();
#pragma unroll 1
    for (int it = 0; it < 5; ++it) {
        const int t0 = it * 6;
        GTN(0, 2, t0 + 0, bfA0, bfA1, bfA2, bfA3, bfB0, bfB1, bfB2, bfB3, 1, 1, "6");
        GTN(1, 0, t0 + 1, bfB0, bfB1, bfB2, bfB3, bfA0, bfA1, bfA2, bfA3, 1, 1, "6");
        GTN(2, 1, t0 + 2, bfA0, bfA1, bfA2, bfA3, bfB0, bfB1, bfB2, bfB3, 1, 1, "6");
        GTN(0, 2, t0 + 3, bfB0, bfB1, bfB2, bfB3, bfA0, bfA1, bfA2, bfA3, 1, 1, "6");
        GTN(1, 0, t0 + 4, bfA0, bfA1, bfA2, bfA3, bfB0, bfB1, bfB2, bfB3, 1, 1, "6");
        GTN(2, 1, t0 + 5, bfB0, bfB1, bfB2, bfB3, bfA0, bfA1, bfA2, bfA3, 1, 1, "6");
    }
    GTN(0, 2, 30, bfA0, bfA1, bfA2, bfA3, bfB0, bfB1, bfB2, bfB3, 0, 1, "4");
    GTN(1, 0, 31, bfB0, bfB1, bfB2, bfB3, bfA0, bfA1, bfA2, bfA3, 0, 0, "0");
    __syncthreads();

    const int sidx = nt >> 3;
    float bv[4];
#pragma unroll
    for (int n = 0; n < 4; ++n) bv[n] = bias[nt * 128 + wn * 64 + n * 16 + fr];

    unsigned short* Cs = (unsigned short*)smem;

    if (sidx < 2) {
        unsigned short* dstb = (sidx == 0) ? qb : kb;
        const float sc = (sidx == 0) ? 0.1803368801111f : 1.0f;
#pragma unroll
        for (int p = 0; p < 2; ++p) {
            if ((wm >> 1) == p) {
                const int r0 = (wm & 1) * 64;
#pragma unroll
                for (int m = 0; m < 4; ++m)
#pragma unroll
                    for (int n = 0; n < 4; ++n)
#pragma unroll
                        for (int r = 0; r < 4; ++r)
                            Cs[(r0 + m * 16 + kg * 4 + r) * 136 + wn * 64 + n * 16 + fr] =
                                f2b((acc[m][n][r] + bv[n]) * sc);
            }
            __syncthreads();
#pragma unroll
            for (int itc = 0; itc < 4; ++itc) {
                const int task = itc * 512 + tid;
                const int rl = task >> 4;
                const int i16 = task & 15;
                const int t = mt * 256 + p * 128 + rl;
                const int b_ = t >> 10, s = t & 1023;
                const int head = ((nt * 128 + i16 * 8) >> 6) & 15;
                u32x4 v = *reinterpret_cast<const u32x4*>(Cs + rl * 136 + i16 * 8);
                *reinterpret_cast<u32x4*>(
                    dstb + ((size_t)(b_ * 16 + head) * 1024 + s) * 64 + (i16 & 7) * 8) = v;
            }
            __syncthreads();
        }
    } else {
#pragma unroll
        for (int p = 0; p < 2; ++p) {
            if ((wm >> 1) == p) {
                const int r0 = (wm & 1) * 64;
#pragma unroll
                for (int m = 0; m < 4; ++m)
#pragma unroll
                    for (int n = 0; n < 4; ++n)
#pragma unroll
                        for (int j = 0; j < 2; ++j) {
                            unsigned int pk = pack2(acc[m][n][2 * j] + bv[n],
                                                    acc[m][n][2 * j + 1] + bv[n]);
                            *reinterpret_cast<unsigned int*>(
                                Cs + (wn * 64 + n * 16 + fr) * 136
                                   + r0 + m * 16 + kg * 4 + 2 * j) = pk;
                        }
            }
            __syncthreads();
#pragma unroll
            for (int itc = 0; itc < 4; ++itc) {
                const int task = itc * 512 + tid;
                const int c = task >> 4;
                const int i16 = task & 15;
                const int col = nt * 128 + c;
                const int head = (col >> 6) & 15;
                const int d = col & 63;
                const int b_ = (mt * 256) >> 10;
                const int s0 = (mt * 256 & 1023) + p * 128 + i16 * 8;
                u32x4 v = *reinterpret_cast<const u32x4*>(Cs + c * 136 + i16 * 8);
                *reinterpret_cast<u32x4*>(
                    vb + (size_t)((b_ * 16 + head) * 64 + d) * 1024 + s0) = v;
            }
            __syncthreads();
        }
    }
#undef STAGE_FULL
#undef BLOAD
#undef MMn
#undef GTN
}

// ---------------- flash attention (swapped QK^T, permuted-K LDS) ----------
// grid: 128 bh * 8 qtiles of 128 rows; block 256 (4 waves x 32 q). KVB=64,
// qf=2 -> ~120 live VGPR; __launch_bounds__(256,4) targets 4 waves/SIMD
// (4 blocks/CU, grid 1024 = exactly 4/CU) to hide barrier/exp latency
// (r13 showed LDS-traffic halving = null -> latency-bound).
#define KVB 64
__global__ __launch_bounds__(256, 4) void attn_kernel(
    const unsigned short* __restrict__ qb,
    const unsigned short* __restrict__ kb,
    const unsigned short* __restrict__ vb,
    float* __restrict__ out)
{
    __shared__ __align__(16) char asmem[32768];  // 2 bufs x (K 8K + V 8K)
    const int tid = threadIdx.x;
    const int lane = tid & 63, w = tid >> 6;
    // XCD-chunked swizzle: 1024 = 8 * 128 (bijective)
    const int wg = (blockIdx.x & 7) * 128 + (blockIdx.x >> 3);
    const int bh = wg >> 3;
    const int qt = wg & 7;
    const int b_ = bh >> 4, h_ = bh & 15;
    const int fr = lane & 15, kg = lane >> 4;

    const unsigned short* qp = qb + ((size_t)bh * 1024 + qt * 128) * 64;
    const unsigned short* kp = kb + (size_t)bh * 1024 * 64;
    const unsigned short* vp = vb + (size_t)bh * 64 * 1024;

    bf16x8 qfr[2][2];
#pragma unroll
    for (int qf = 0; qf < 2; ++qf) {
        const unsigned short* qr = qp + (w * 32 + qf * 16 + fr) * 64 + kg * 8;
        qfr[qf][0] = *reinterpret_cast<const bf16x8*>(qr);
        qfr[qf][1] = *reinterpret_cast<const bf16x8*>(qr + 32);
    }

    float m_q[2] = {-1e30f, -1e30f}, l_q[2] = {0.f, 0.f};
    f32x4 o_acc[2][4] = {};

    const int ksr = w * 8 + (lane >> 3);   // staging row within 32-row group
    const int kcb = (lane & 7) * 16;       // granule byte within 128B row

#define ASTAGE(buf, kvt) do {                                                  \
    const int kv0_ = (kvt) * KVB;                                              \
    char* Kb_ = asmem + (buf) * 16384 + w * 1024;                              \
    char* Vb_ = Kb_ + 8192;                                                    \
    _Pragma("unroll")                                                          \
    for (int i = 0; i < 2; ++i) {                                              \
        const int st = i * 32 + ksr;                                           \
        const int key = ((st >> 5) << 5) | (((st & 15) >> 2) << 3)             \
                      | (((st >> 4) & 1) << 2) | (st & 3);                     \
        const int scb = kcb ^ ((st & 7) << 4);                                 \
        gload_lds16(kp + (size_t)(kv0_ + key) * 64 + (scb >> 1),               \
                    Kb_ + i * 4096);                                           \
        const int d_ = i * 32 + ksr;                                           \
        const int svb = kcb ^ ((d_ & 7) << 4);                                 \
        gload_lds16(vp + (size_t)d_ * 1024 + kv0_ + (svb >> 1),                \
                    Vb_ + i * 4096);                                           \
    }                                                                          \
} while (0)

#define ACOMP(buf) do {                                                        \
    const char* Kb = asmem + (buf) * 16384;                                    \
    const char* Vb = Kb + 8192;                                                \
    f32x4 sacc[2][4] = {};                                                     \
    __builtin_amdgcn_s_setprio(1);                                             \
    _Pragma("unroll")                                                          \
    for (int jt = 0; jt < 4; ++jt) {                                           \
        _Pragma("unroll")                                                      \
        for (int ks = 0; ks < 2; ++ks) {                                       \
            const int cb = (ks * 64 + kg * 16) ^ ((fr & 7) << 4);              \
            bf16x8 kf = *reinterpret_cast<const bf16x8*>(                      \
                Kb + (jt * 16 + fr) * 128 + cb);                               \
            _Pragma("unroll")                                                  \
            for (int qf = 0; qf < 2; ++qf)                                     \
                sacc[qf][jt] = __builtin_amdgcn_mfma_f32_16x16x32_bf16(        \
                    kf, qfr[qf][ks], sacc[qf][jt], 0, 0, 0);                   \
        }                                                                      \
    }                                                                          \
    __builtin_amdgcn_s_setprio(0);                                             \
    unsigned int P2[2][4][2];                                                  \
    _Pragma("unroll")                                                          \
    for (int qf = 0; qf < 2; ++qf) {                                           \
        float mx = -1e30f;                                                     \
        _Pragma("unroll")                                                      \
        for (int jt = 0; jt < 4; ++jt) {                                       \
            float a = fmaxf(fmaxf(sacc[qf][jt][0], sacc[qf][jt][1]),           \
                            fmaxf(sacc[qf][jt][2], sacc[qf][jt][3]));          \
            mx = fmaxf(mx, a);                                                 \
        }                                                                      \
        mx = fmaxf(mx, __shfl_xor(mx, 16, 64));                                \
        mx = fmaxf(mx, __shfl_xor(mx, 32, 64));                                \
        if (__any(mx > m_q[qf] + 8.0f)) {                                      \
            const float mn = fmaxf(m_q[qf], mx);                               \
            const float corr = __builtin_amdgcn_exp2f(m_q[qf] - mn);           \
            m_q[qf] = mn;                                                      \
            l_q[qf] *= corr;                                                   \
            float cr[4];                                                       \
            _Pragma("unroll")                                                  \
            for (int r = 0; r < 4; ++r)                                        \
                cr[r] = __shfl(corr, kg * 4 + r, 64);                          \
            _Pragma("unroll")                                                  \
            for (int d0 = 0; d0 < 4; ++d0)                                     \
                _Pragma("unroll")                                              \
                for (int r = 0; r < 4; ++r) o_acc[qf][d0][r] *= cr[r];         \
        }                                                                      \
        const float mn_ = m_q[qf];                                             \
        float rs = 0.f;                                                        \
        _Pragma("unroll")                                                      \
        for (int jt = 0; jt < 4; ++jt) {                                       \
            float p0 = __builtin_amdgcn_exp2f(sacc[qf][jt][0] - mn_);          \
            float p1 = __builtin_amdgcn_exp2f(sacc[qf][jt][1] - mn_);          \
            float p2 = __builtin_amdgcn_exp2f(sacc[qf][jt][2] - mn_);          \
            float p3 = __builtin_amdgcn_exp2f(sacc[qf][jt][3] - mn_);          \
            rs += (p0 + p1) + (p2 + p3);                                       \
            P2[qf][jt][0] = pack2(p0, p1);                                     \
            P2[qf][jt][1] = pack2(p2, p3);                                     \
        }                                                                      \
        rs += __shfl_xor(rs, 16, 64);                                          \
        rs += __shfl_xor(rs, 32, 64);                                          \
        l_q[qf] += rs;                                                         \
    }                                                                          \
    __builtin_amdgcn_s_setprio(1);                                             \
    _Pragma("unroll")                                                          \
    for (int c = 0; c < 2; ++c) {                                              \
        bf16x8 pa[2];                                                          \
        _Pragma("unroll")                                                      \
        for (int qf = 0; qf < 2; ++qf) {                                       \
            u32x4 pw = { P2[qf][2 * c][0], P2[qf][2 * c][1],                   \
                         P2[qf][2 * c + 1][0], P2[qf][2 * c + 1][1] };         \
            pa[qf] = __builtin_bit_cast(bf16x8, pw);                           \
        }                                                                      \
        _Pragma("unroll")                                                      \
        for (int d0 = 0; d0 < 4; ++d0) {                                       \
            const int dd = d0 * 16 + fr;                                       \
            const int cbv = (c * 64 + kg * 16) ^ ((dd & 7) << 4);              \
            bf16x8 vf = *reinterpret_cast<const bf16x8*>(Vb + dd * 128 + cbv); \
            _Pragma("unroll")                                                  \
            for (int qf = 0; qf < 2; ++qf)                                     \
                o_acc[qf][d0] = __builtin_amdgcn_mfma_f32_16x16x32_bf16(       \
                    pa[qf], vf, o_acc[qf][d0], 0, 0, 0);                       \
        }                                                                      \
    }                                                                          \
    __builtin_amdgcn_s_setprio(0);                                             \
} while (0)

    ASTAGE(0, 0);
#pragma unroll 1
    for (int t = 0; t < 15; ++t) {
        ASTAGE((t + 1) & 1, t + 1);
        asm volatile("s_waitcnt vmcnt(4) lgkmcnt(0)" ::: "memory");
        __builtin_amdgcn_s_barrier();
        ACOMP(t & 1);
        asm volatile("s_waitcnt lgkmcnt(0)" ::: "memory");
        __builtin_amdgcn_s_barrier();
    }
    asm volatile("s_waitcnt vmcnt(0) lgkmcnt(0)" ::: "memory");
    __builtin_amdgcn_s_barrier();
    ACOMP(1);

    // epilogue: normalize and write fp32 out[t][h*64+d]
#pragma unroll
    for (int qf = 0; qf < 2; ++qf) {
        float linv[4];
#pragma unroll
        for (int r = 0; r < 4; ++r)
            linv[r] = 1.0f / __shfl(l_q[qf], kg * 4 + r, 64);
        const int trow = b_ * 1024 + qt * 128 + w * 32 + qf * 16;
#pragma unroll
        for (int d0 = 0; d0 < 4; ++d0) {
            const int c = h_ * 64 + d0 * 16 + fr;
#pragma unroll
            for (int r = 0; r < 4; ++r)
                out[(size_t)(trow + kg * 4 + r) * 1024 + c] = o_acc[qf][d0][r] * linv[r];
        }
    }
#undef ASTAGE
#undef ACOMP
}

extern "C" void kernel_launch(void* const* d_in, const int* in_sizes, int n_in,
                              void* d_out, int out_size, void* d_ws, size_t ws_size,
                              hipStream_t stream)
{
    const float* hs   = (const float*)d_in[0];
    const float* Wqkv = (const float*)d_in[1];
    const float* Bqkv = (const float*)d_in[2];
    float* out = (float*)d_out;

    char* ws = (char*)d_ws;
    unsigned short* hsb = (unsigned short*)(ws);                        // 16 MB
    unsigned short* wb  = (unsigned short*)(ws + (size_t)16 * 1048576); //  6 MB
    unsigned short* qb  = (unsigned short*)(ws + (size_t)22 * 1048576); // 16 MB
    unsigned short* kb  = (unsigned short*)(ws + (size_t)38 * 1048576); // 16 MB
    unsigned short* vb  = (unsigned short*)(ws + (size_t)54 * 1048576); // 16 MB

    cvt2_kernel<<<2048, 256, 0, stream>>>(hs, hsb, 8192 * 1024 / 4,
                                          Wqkv, wb, 3072 * 1024 / 8);
    qkv_gemm<<<768, 512, 0, stream>>>(hsb, wb, Bqkv, qb, kb, vb);
    attn_kernel<<<1024, 256, 0, stream>>>(qb, kb, vb, out);
}